// Round 9
// baseline (896.588 us; speedup 1.0000x reference)
//
#include <hip/hip_runtime.h>
#include <stdint.h>

#define DI __device__ __forceinline__

constexpr int Bn = 32, Cc = 64, Wn = 96, Hn = 96, Ln = 32, NG = 128, OUTC = 256;
constexpr int SEQ = 96;
constexpr long long NPIX = (long long)Bn * Wn * Hn;   // 294912
constexpr int GRAM_BLOCKS = 128;
constexpr int PIX_PER_BLOCK = (int)(NPIX / GRAM_BLOCKS); // 2304

typedef __attribute__((ext_vector_type(8))) short bf16x8;
typedef __attribute__((ext_vector_type(4))) float f32x4;

DI float tanhf_(float x) { return 1.0f - 2.0f / (__expf(2.0f * x) + 1.0f); } // NaN-free both tails
DI float sigmf_(float x) { return 1.0f / (1.0f + __expf(-x)); }
DI float bf2f(unsigned short u) { return __uint_as_float(((unsigned)u) << 16); }
DI unsigned short f2bf(float f) {
    unsigned u = __float_as_uint(f);
    u += 0x7FFFu + ((u >> 16) & 1u);   // RNE
    return (unsigned short)(u >> 16);
}

// ---------------------------------------------------------------------------
// Input-projection GEMM via MFMA. One block per chain (b,q); A = 96x64 tile.
// xg layout (R9 change): [chain][dir][t][glow=g&15][ghigh=g>>4] bf16 —
// matches the wave-independent recurrent kernel: per step a lane loads
// 4 x b128 (glow = rg*4+r), each covering the 8 gate-tile (ghigh) values.
// Epilogue is 48 scalar u16 stores/thread (16B-stride gaps are filled by
// sibling waves of the same block -> L2 merge).
// TRANSPOSE=1: input x f32 [B,C,W,H], q=w, t=h (transpose in staging).
// TRANSPOSE=0: input v bf16 [B,H,W,64], q=h, t=w (contiguous slab).
// ---------------------------------------------------------------------------
template<int TRANSPOSE>
__global__ __launch_bounds__(512, 4)
void xg_kernel(const void* __restrict__ in_,
               const float* __restrict__ wih_f, const float* __restrict__ bih_f,
               const float* __restrict__ bhh_f,
               const float* __restrict__ wih_b, const float* __restrict__ bih_b,
               const float* __restrict__ bhh_b,
               unsigned short* __restrict__ xg)
{
    __shared__ alignas(16) unsigned char AsB[96 * 128];    // bf16 A, swizzled
    __shared__ alignas(16) unsigned char WtB[256 * 128];   // bf16 W^T, swizzled
    __shared__ float biasS[256];

    const int tid = threadIdx.x;
    const int b = blockIdx.x / 96, q = blockIdx.x % 96;

    if (tid < 256) {
        int o = tid, g = o & 127;
        biasS[o] = (o < 128) ? (bih_f[g] + bhh_f[g]) : (bih_b[g] + bhh_b[g]);
    }
    for (int i4 = tid; i4 < 4096; i4 += 512) {
        int wrow = i4 >> 4, k4 = i4 & 15;
        const float* wsrc = (wrow < 128 ? wih_f : wih_b) + (size_t)(wrow & 127) * 64 + k4 * 4;
        float4 v = *(const float4*)wsrc;
        ushort4 p; p.x = f2bf(v.x); p.y = f2bf(v.y); p.z = f2bf(v.z); p.w = f2bf(v.w);
        *(ushort4*)(WtB + wrow * 128 + ((k4 * 8) ^ ((wrow & 7) << 4))) = p;
    }
    if (TRANSPOSE) {
        const float* in = (const float*)in_;
        for (int i = tid; i < 1536; i += 512) {
            int c = i / 24, h4 = i - c * 24;
            float4 v = *(const float4*)(in + (((size_t)b * 64 + c) * 96 + q) * 96 + 4 * h4);
            int r0 = 4 * h4;
            float vv[4] = {v.x, v.y, v.z, v.w};
#pragma unroll
            for (int j = 0; j < 4; ++j) {
                int row = r0 + j;
                *(unsigned short*)(AsB + row * 128 + ((c * 2) ^ ((row & 7) << 4))) = f2bf(vv[j]);
            }
        }
    } else {
        const unsigned short* src = (const unsigned short*)in_ + (size_t)blockIdx.x * 6144;
        for (int i8 = tid; i8 < 768; i8 += 512) {
            int row = i8 >> 3, k8 = i8 & 7;
            bf16x8 p = *(const bf16x8*)(src + (size_t)i8 * 8);
            *(bf16x8*)(AsB + row * 128 + ((k8 * 16) ^ ((row & 7) << 4))) = p;
        }
    }
    __syncthreads();

    const int wv = tid >> 6, lane = tid & 63;
    const int mbase = (wv >> 2) * 48;
    const int nbase = (wv & 3) * 64;
    const int lrow = lane & 15, lk = (lane >> 4) * 8;

    f32x4 acc[3][4];
#pragma unroll
    for (int m = 0; m < 3; ++m)
#pragma unroll
        for (int n = 0; n < 4; ++n)
            acc[m][n] = (f32x4){0.f, 0.f, 0.f, 0.f};

#pragma unroll
    for (int ks = 0; ks < 2; ++ks) {
        const int kb = (ks * 32 + lk) * 2;
        bf16x8 am[3], bn[4];
#pragma unroll
        for (int m = 0; m < 3; ++m) {
            int row = mbase + m * 16 + lrow;
            am[m] = *(const bf16x8*)(AsB + row * 128 + (kb ^ ((row & 7) << 4)));
        }
#pragma unroll
        for (int n = 0; n < 4; ++n) {
            int o = nbase + n * 16 + lrow;
            bn[n] = *(const bf16x8*)(WtB + o * 128 + (kb ^ ((o & 7) << 4)));
        }
#pragma unroll
        for (int m = 0; m < 3; ++m)
#pragma unroll
            for (int n = 0; n < 4; ++n)
                acc[m][n] = __builtin_amdgcn_mfma_f32_16x16x32_bf16(am[m], bn[n], acc[m][n], 0, 0, 0);
    }

    // write [dir][t][glow][ghigh]: o = dir*128 + g; glow = g&15 = lrow; ghigh = (o>>4)&7
    unsigned short* ob = xg + (size_t)blockIdx.x * 24576;
#pragma unroll
    for (int n = 0; n < 4; ++n) {
        const int o = nbase + n * 16 + lrow;
        const float bv = biasS[o];
        const size_t dbase = (size_t)(o >> 7) * 12288 + ((o >> 4) & 7);
#pragma unroll
        for (int m = 0; m < 3; ++m) {
            const int t0 = mbase + m * 16 + (lane >> 4) * 4;
#pragma unroll
            for (int r = 0; r < 4; ++r) {
                ob[dbase + (size_t)(t0 + r) * 128 + lrow * 8] = f2bf(acc[m][n][r] + bv);
            }
        }
    }
}

// ---------------------------------------------------------------------------
// Recurrent BiLSTM, WAVE-INDEPENDENT (R9 rewrite). R8 evidence (from totals):
// 133us/pass — 2 block barriers x 96 steps with 4 waves/block dominated.
// Here each WAVE owns 16 (chain) units of one dir, computing ALL 8 gate
// tiles itself: G[128][16] = Whh[128x32] @ H[32x16] as 8 MFMAs. C-layout
// gives lane (chain=n_, rg) gates {16*tt + rg*4 + j} -> all of i,f,g,o for
// cells {s*16+rg*4+j} -> cell update LANE-LOCAL; h crosses only within the
// wave via private LDS (in-order DS pipe, NO barriers at all).
// xg read: 4 x b128/lane/step from [chain][dir][t][glow][ghigh], prefetched
// one step ahead. h LDS: [chain][k] bf16, 80B stride (16B-aligned, 2-way
// bank alias = free). Grid: 6144 units / 16 = 384 waves = 96 blocks.
// ---------------------------------------------------------------------------
template<int VERT>
__global__ __launch_bounds__(256, 1)
void lstm_rec(const unsigned short* __restrict__ xg,
              const float* __restrict__ whh_f, const float* __restrict__ whh_b,
              unsigned short* __restrict__ outU)
{
    __shared__ alignas(16) unsigned char hbufS[4][1280];   // per-wave h[16 chains][32 k] bf16, 80B/chain

    const int tid = threadIdx.x;
    const int wv = tid >> 6, lane = tid & 63;
    const int wgid = blockIdx.x * 4 + wv;          // [0, 768)
    const int dir = wgid & 1, group = wgid >> 1;   // group in [0, 384)
    const int n_ = lane & 15, rg = lane >> 4;
    const int chain = group * 16 + n_;             // 96 % 16 == 0 -> b uniform per wave
    const int b = group / 6;
    const int q = (group - b * 6) * 16 + n_;

    unsigned char* hb = hbufS[wv];

    // A fragments: af[tt] = Whh rows tt*16+n_, k = rg*8..+8 (bf16)
    const float* whh = dir ? whh_b : whh_f;
    bf16x8 af[8];
#pragma unroll
    for (int tt = 0; tt < 8; ++tt) {
        const float* s = whh + (size_t)(tt * 16 + n_) * 32 + rg * 8;
        float4 a0 = *(const float4*)s, a1 = *(const float4*)(s + 4);
        af[tt][0] = f2bf(a0.x); af[tt][1] = f2bf(a0.y);
        af[tt][2] = f2bf(a0.z); af[tt][3] = f2bf(a0.w);
        af[tt][4] = f2bf(a1.x); af[tt][5] = f2bf(a1.y);
        af[tt][6] = f2bf(a1.z); af[tt][7] = f2bf(a1.w);
    }
    // zero this wave's h buffer (1280 B = 320 u32); wave-local, DS in-order
    for (int i = lane; i < 320; i += 64) ((unsigned*)hb)[i] = 0u;

    // xg per-lane base: [chain][dir][t][glow][ghigh]; glow = rg*4 + r
    const unsigned short* xbase = xg + (size_t)chain * 24576 + (size_t)dir * 12288
                                     + (size_t)(rg * 4) * 8;

    float cc[2][4];
#pragma unroll
    for (int s = 0; s < 2; ++s)
#pragma unroll
        for (int j = 0; j < 4; ++j) cc[s][j] = 0.f;

    bf16x8 xv[4], xn[4];
    {
        const int t0 = dir ? 95 : 0;
#pragma unroll
        for (int r = 0; r < 4; ++r)
            xv[r] = *(const bf16x8*)(xbase + (size_t)t0 * 128 + r * 8);
    }

    for (int st = 0; st < SEQ; ++st) {
        const int t = dir ? 95 - st : st;
        const int tn = (st < 95) ? (dir ? t - 1 : t + 1) : t;
#pragma unroll
        for (int r = 0; r < 4; ++r)
            xn[r] = *(const bf16x8*)(xbase + (size_t)tn * 128 + r * 8);

        // B fragment: h[k = rg*8..+8][chain n_]
        const bf16x8 hf = *(const bf16x8*)(hb + n_ * 80 + rg * 16);
        f32x4 ac[8];
#pragma unroll
        for (int tt = 0; tt < 8; ++tt)
            ac[tt] = __builtin_amdgcn_mfma_f32_16x16x32_bf16(af[tt], hf,
                         (f32x4){0.f, 0.f, 0.f, 0.f}, 0, 0, 0);

#pragma unroll
        for (int s = 0; s < 2; ++s) {
            ushort4 hp;
            unsigned short* hpp = (unsigned short*)&hp;
#pragma unroll
            for (int j = 0; j < 4; ++j) {
                const float iv = sigmf_(ac[0 + s][j] + bf2f((unsigned short)xv[j][0 + s]));
                const float fv = sigmf_(ac[2 + s][j] + bf2f((unsigned short)xv[j][2 + s]));
                const float gv = tanhf_(ac[4 + s][j] + bf2f((unsigned short)xv[j][4 + s]));
                const float ov = sigmf_(ac[6 + s][j] + bf2f((unsigned short)xv[j][6 + s]));
                cc[s][j] = fmaf(fv, cc[s][j], iv * gv);
                hpp[j] = f2bf(ov * tanhf_(cc[s][j]));
            }
            // wave-local h writeback: cells s*16+rg*4..+4 of chain n_
            *(ushort4*)(hb + n_ * 80 + (s * 16 + rg * 4) * 2) = hp;
            // global output (bf16): 8B per lane, 32B dense per chain per instr
            const int cbase = dir * 32 + s * 16 + rg * 4;
            const size_t oidx = VERT
                ? ((((size_t)b * 96 + t) * 96 + q) * 64 + cbase)
                : ((((size_t)b * 96 + q) * 96 + t) * 64 + cbase);
            *(ushort4*)(outU + oidx) = hp;
        }
#pragma unroll
        for (int r = 0; r < 4; ++r) xv[r] = xn[r];
    }
}

// ---------------------------------------------------------------------------
// Partial Gram (64x64) + channel-sum (64) of hh over this block's pixel chunk.
// ---------------------------------------------------------------------------
__global__ __launch_bounds__(256)
void gram_partial(const unsigned short* __restrict__ hh, float* __restrict__ part)
{
    __shared__ float xs[64][64];
    __shared__ float red[4160];
    const int tid = threadIdx.x;
    for (int e = tid; e < 4160; e += 256) red[e] = 0.0f;
    const int lane = tid & 63, wv = tid >> 6;
    const int li = lane >> 3, lj = lane & 7;
    float acc[8][8]; float macc[8];
#pragma unroll
    for (int i = 0; i < 8; ++i) {
        macc[i] = 0.f;
#pragma unroll
        for (int j = 0; j < 8; ++j) acc[i][j] = 0.f;
    }
    const size_t pix0 = (size_t)blockIdx.x * PIX_PER_BLOCK;
    for (int tile = 0; tile < PIX_PER_BLOCK / 64; ++tile) {
        __syncthreads();
        const unsigned short* src = hh + (pix0 + tile * 64) * 64;
#pragma unroll
        for (int r = 0; r < 4; ++r) {
            int idx4 = tid + 256 * r;
            ushort4 v = ((const ushort4*)src)[idx4];
            int fi = idx4 * 4; int px = fi >> 6; int c = fi & 63;
            xs[px][c] = bf2f(v.x); xs[px][c + 1] = bf2f(v.y);
            xs[px][c + 2] = bf2f(v.z); xs[px][c + 3] = bf2f(v.w);
        }
        __syncthreads();
        for (int p = wv * 16; p < wv * 16 + 16; ++p) {
            float4 ra = *(const float4*)&xs[p][8 * li];
            float4 rb = *(const float4*)&xs[p][8 * li + 4];
            float4 ca = *(const float4*)&xs[p][8 * lj];
            float4 cb = *(const float4*)&xs[p][8 * lj + 4];
            float r[8] = {ra.x, ra.y, ra.z, ra.w, rb.x, rb.y, rb.z, rb.w};
            float cl[8] = {ca.x, ca.y, ca.z, ca.w, cb.x, cb.y, cb.z, cb.w};
#pragma unroll
            for (int i = 0; i < 8; ++i) {
#pragma unroll
                for (int j = 0; j < 8; ++j) acc[i][j] = fmaf(r[i], cl[j], acc[i][j]);
            }
            if (lj == 0) {
#pragma unroll
                for (int i = 0; i < 8; ++i) macc[i] += r[i];
            }
        }
    }
    __syncthreads();
#pragma unroll
    for (int i = 0; i < 8; ++i)
#pragma unroll
        for (int j = 0; j < 8; ++j)
            atomicAdd(&red[(8 * li + i) * 64 + 8 * lj + j], acc[i][j]);
    if (lj == 0)
        for (int i = 0; i < 8; ++i) atomicAdd(&red[4096 + 8 * li + i], macc[i]);
    __syncthreads();
    for (int e = tid; e < 4160; e += 256) part[(size_t)blockIdx.x * 4160 + e] = red[e];
}

__global__ void gram_reduce(const float* __restrict__ part, float* __restrict__ M)
{
    int e = blockIdx.x * 256 + threadIdx.x;
    if (e >= 4160) return;
    double s = 0.0;
    for (int p = 0; p < GRAM_BLOCKS; ++p) s += (double)part[(size_t)p * 4160 + e];
    M[e] = (float)s;
}

// Per-output-channel affine coefficients A,B such that out = A*(w_o . u) + B.
// Weights rounded through bf16 so A/B match the bf16-MFMA conv exactly.
__global__ __launch_bounds__(256)
void stats_kernel(const float* __restrict__ M, const float* __restrict__ cw,
                  const float* __restrict__ cb, const float* __restrict__ bg,
                  const float* __restrict__ bb,
                  float* __restrict__ Aout, float* __restrict__ Bout)
{
    __shared__ float Ml[4160];
    const int tid = threadIdx.x;
    for (int e = tid; e < 4160; e += 256) Ml[e] = M[e];
    __syncthreads();
    float wr[64];
#pragma unroll
    for (int c = 0; c < 64; ++c) wr[c] = bf2f(f2bf(cw[tid * 64 + c]));
    float s1 = 0.f;
#pragma unroll
    for (int c = 0; c < 64; ++c) s1 = fmaf(wr[c], Ml[4096 + c], s1);
    float s2 = 0.f;
    for (int c = 0; c < 64; ++c) {
        const float* Mr = &Ml[c * 64];
        float t = 0.f;
#pragma unroll
        for (int d = 0; d < 64; ++d) t = fmaf(wr[d], Mr[d], t);
        s2 = fmaf(wr[c], t, s2);
    }
    const double invN = 1.0 / (double)NPIX;
    double cbo = (double)cb[tid];
    double mu = (double)s1 * invN + cbo;
    double ey2 = (double)s2 * invN + 2.0 * cbo * ((double)s1 * invN) + cbo * cbo;
    double var = ey2 - mu * mu;
    double A = (double)bg[tid] / sqrt(var + 1e-5);
    Aout[tid] = (float)A;
    Bout[tid] = (float)((double)bb[tid] + A * (cbo - mu));
}

// ---------------------------------------------------------------------------
// Fused 1x1 conv + BN apply via MFMA. Block = (b,w): D[96 h][256 o].
// ---------------------------------------------------------------------------
__global__ __launch_bounds__(512, 2)
void conv_bn_kernel(const unsigned short* __restrict__ hh, const float* __restrict__ cw,
                    const float* __restrict__ Aarr, const float* __restrict__ Barr,
                    float* __restrict__ out)
{
    __shared__ alignas(16) unsigned char UsB[96 * 128];    // bf16 U, swizzled
    __shared__ alignas(16) unsigned char WtB[256 * 128];   // bf16 conv W, swizzled

    const int tid = threadIdx.x;
    const int b = blockIdx.x / 96, w = blockIdx.x % 96;

    for (int i4 = tid; i4 < 4096; i4 += 512) {
        int wrow = i4 >> 4, k4 = i4 & 15;
        float4 v = *(const float4*)(cw + (size_t)wrow * 64 + k4 * 4);
        ushort4 p; p.x = f2bf(v.x); p.y = f2bf(v.y); p.z = f2bf(v.z); p.w = f2bf(v.w);
        *(ushort4*)(WtB + wrow * 128 + ((k4 * 8) ^ ((wrow & 7) << 4))) = p;
    }
    for (int i = tid; i < 1536; i += 512) {
        int row = i >> 4, k4 = i & 15;   // row = h
        ushort4 p = *(const ushort4*)(hh + (((size_t)b * 96 + row) * 96 + w) * 64 + k4 * 4);
        *(ushort4*)(UsB + row * 128 + ((k4 * 8) ^ ((row & 7) << 4))) = p;
    }
    __syncthreads();

    const int wv = tid >> 6, lane = tid & 63;
    const int mbase = (wv >> 2) * 48, nbase = (wv & 3) * 64;
    const int lrow = lane & 15, lk = (lane >> 4) * 8;

    f32x4 acc[3][4];
#pragma unroll
    for (int m = 0; m < 3; ++m)
#pragma unroll
        for (int n = 0; n < 4; ++n)
            acc[m][n] = (f32x4){0.f, 0.f, 0.f, 0.f};

#pragma unroll
    for (int ks = 0; ks < 2; ++ks) {
        const int kb = (ks * 32 + lk) * 2;
        bf16x8 am[3], bn[4];
#pragma unroll
        for (int m = 0; m < 3; ++m) {
            int row = mbase + m * 16 + lrow;
            am[m] = *(const bf16x8*)(UsB + row * 128 + (kb ^ ((row & 7) << 4)));
        }
#pragma unroll
        for (int n = 0; n < 4; ++n) {
            int o = nbase + n * 16 + lrow;
            bn[n] = *(const bf16x8*)(WtB + o * 128 + (kb ^ ((o & 7) << 4)));
        }
#pragma unroll
        for (int m = 0; m < 3; ++m)
#pragma unroll
            for (int n = 0; n < 4; ++n)
                acc[m][n] = __builtin_amdgcn_mfma_f32_16x16x32_bf16(am[m], bn[n], acc[m][n], 0, 0, 0);
    }

    const int hbase0 = (lane >> 4) * 4;
#pragma unroll
    for (int n = 0; n < 4; ++n) {
        const int o = nbase + n * 16 + lrow;
        const float Ao = Aarr[o], Bo = Barr[o];
        float* obase = out + (((size_t)b * 256 + o) * 96 + w) * 96;
#pragma unroll
        for (int m = 0; m < 3; ++m) {
            const int h0 = mbase + m * 16 + hbase0;
            float4 res;
            res.x = fmaf(Ao, acc[m][n][0], Bo);
            res.y = fmaf(Ao, acc[m][n][1], Bo);
            res.z = fmaf(Ao, acc[m][n][2], Bo);
            res.w = fmaf(Ao, acc[m][n][3], Bo);
            *(float4*)(obase + h0) = res;
        }
    }
}

extern "C" void kernel_launch(void* const* d_in, const int* in_sizes, int n_in,
                              void* d_out, int out_size, void* d_ws, size_t ws_size,
                              hipStream_t stream)
{
    const float* x       = (const float*)d_in[0];
    const float* v_wih_f = (const float*)d_in[1];
    const float* v_whh_f = (const float*)d_in[2];
    const float* v_bih_f = (const float*)d_in[3];
    const float* v_bhh_f = (const float*)d_in[4];
    const float* v_wih_b = (const float*)d_in[5];
    const float* v_whh_b = (const float*)d_in[6];
    const float* v_bih_b = (const float*)d_in[7];
    const float* v_bhh_b = (const float*)d_in[8];
    const float* h_wih_f = (const float*)d_in[9];
    const float* h_whh_f = (const float*)d_in[10];
    const float* h_bih_f = (const float*)d_in[11];
    const float* h_bhh_f = (const float*)d_in[12];
    const float* h_wih_b = (const float*)d_in[13];
    const float* h_whh_b = (const float*)d_in[14];
    const float* h_bih_b = (const float*)d_in[15];
    const float* h_bhh_b = (const float*)d_in[16];
    const float* conv_w  = (const float*)d_in[17];
    const float* conv_b  = (const float*)d_in[18];
    const float* bn_g    = (const float*)d_in[19];
    const float* bn_b    = (const float*)d_in[20];
    float* out = (float*)d_out;

    // d_out (302 MB) doubles as scratch before conv_bn rewrites all of it:
    //   bytes [0, 151 MB): xg buffer (bf16, [chain][dir][t][glow][ghigh])
    //   tail 37.7 MB: v (bf16 [B,H,W,64]) — vertical LSTM output
    const size_t v_elems = (size_t)Bn * Hn * Wn * 64;   // 18,874,368 bf16
    unsigned short* v_buf = (unsigned short*)(out + (size_t)out_size) - v_elems;
    unsigned short* xgbuf = (unsigned short*)d_out;      // 150,994,944 bytes

    // workspace layout (~40 MB)
    unsigned short* hh = (unsigned short*)d_ws;                       // bf16 [B,H,W,64]
    char* wsb = (char*)d_ws;
    float* part = (float*)(wsb + 37748736);                           // 128 x 4160 f32
    float* M    = (float*)(wsb + 37748736 + 2129920);                 // 4160 f32
    float* Aarr = M + 4160;
    float* Barr = Aarr + 256;

    // vertical pass
    xg_kernel<1><<<3072, 512, 0, stream>>>(x, v_wih_f, v_bih_f, v_bhh_f,
                                           v_wih_b, v_bih_b, v_bhh_b, xgbuf);
    lstm_rec<1><<<96, 256, 0, stream>>>(xgbuf, v_whh_f, v_whh_b, v_buf);
    // horizontal pass
    xg_kernel<0><<<3072, 512, 0, stream>>>(v_buf, h_wih_f, h_bih_f, h_bhh_f,
                                           h_wih_b, h_bih_b, h_bhh_b, xgbuf);
    lstm_rec<0><<<96, 256, 0, stream>>>(xgbuf, h_whh_f, h_whh_b, hh);
    // conv + BN (affine-folded via Gram-matrix stats)
    gram_partial<<<GRAM_BLOCKS, 256, 0, stream>>>(hh, part);
    gram_reduce<<<17, 256, 0, stream>>>(part, M);
    stats_kernel<<<1, 256, 0, stream>>>(M, conv_w, conv_b, bn_g, bn_b, Aarr, Barr);
    conv_bn_kernel<<<3072, 512, 0, stream>>>(hh, conv_w, Aarr, Barr, out);
}

// Round 10
// 591.888 us; speedup vs baseline: 1.5148x; 1.5148x over previous
//
#include <hip/hip_runtime.h>
#include <stdint.h>

#define DI __device__ __forceinline__

constexpr int Bn = 32, Cc = 64, Wn = 96, Hn = 96, Ln = 32, NG = 128, OUTC = 256;
constexpr int SEQ = 96;
constexpr long long NPIX = (long long)Bn * Wn * Hn;   // 294912
constexpr int GRAM_BLOCKS = 128;
constexpr int PIX_PER_BLOCK = (int)(NPIX / GRAM_BLOCKS); // 2304

typedef __attribute__((ext_vector_type(8))) short bf16x8;
typedef __attribute__((ext_vector_type(4))) float f32x4;

DI float tanhf_(float x) { return 1.0f - 2.0f / (__expf(2.0f * x) + 1.0f); } // NaN-free both tails
DI float sigmf_(float x) { return 1.0f / (1.0f + __expf(-x)); }
DI float bf2f(unsigned short u) { return __uint_as_float(((unsigned)u) << 16); }
DI unsigned short f2bf(float f) {
    unsigned u = __float_as_uint(f);
    u += 0x7FFFu + ((u >> 16) & 1u);   // RNE
    return (unsigned short)(u >> 16);
}

union U32x4 { unsigned u[4]; bf16x8 v; };

// ---------------------------------------------------------------------------
// x transpose: [B,C,W,H] f32 -> xT[chain=(b,w)][t=h][c] bf16.  (The horizontal
// pass consumes v, which is already [chain=(b,h)][t=w][c] bf16 — same kernel
// lstm_fused serves both passes.)
// ---------------------------------------------------------------------------
__global__ __launch_bounds__(256)
void transpose_x(const float* __restrict__ x, unsigned short* __restrict__ xT)
{
    __shared__ alignas(16) unsigned char xs[96 * 128];
    const int tid = threadIdx.x;
    const int b = blockIdx.x / 96, q = blockIdx.x % 96;
    for (int i = tid; i < 1536; i += 256) {
        int c = i / 24, h4 = i - c * 24;
        float4 v = *(const float4*)(x + (((size_t)b * 64 + c) * 96 + q) * 96 + 4 * h4);
        float vv[4] = {v.x, v.y, v.z, v.w};
#pragma unroll
        for (int j = 0; j < 4; ++j) {
            int h = 4 * h4 + j;
            *(unsigned short*)(xs + h * 128 + ((c * 2) ^ ((h & 7) << 4))) = f2bf(vv[j]);
        }
    }
    __syncthreads();
    unsigned short* ob = xT + (size_t)blockIdx.x * 6144;
    for (int i = tid; i < 768; i += 256) {
        int row = i >> 3, k8 = i & 7;
        bf16x8 p = *(const bf16x8*)(xs + row * 128 + ((k8 * 16) ^ ((row & 7) << 4)));
        *(bf16x8*)(ob + (size_t)i * 8) = p;
    }
}

// ---------------------------------------------------------------------------
// FUSED BiLSTM (R10): input projection + recurrence in one wave-independent
// kernel. R9 evidence: occupancy 3.7% (96 blocks!) + LDS h-roundtrip on the
// serial path; xg HBM round-trip (151MB w + 151MB r) was pure overhead.
// Here: block = 1 wave = 16 chains x 1 dir; grid 384 -> all 256 CUs.
// Per step: gates = Wih@x_t (K=64: 2 MFMA) + Whh@h (1 MFMA) + bias (C-input),
// 8 gate-tiles => 24 MFMA/step. h kept in REGISTERS; cross-lane h exchange
// via 8 __shfl + 4 selects (wave-synchronous, no LDS, no barriers).
// x streamed from xT[chain][t][c] (2 x b128/lane/step), depth-2 prefetch via
// 3 static register banks. Weights/bias in VGPRs (~200, fine at 1 wave/SIMD).
// ---------------------------------------------------------------------------
#define FLOAD(XA, XB, STI)                                                     \
    if ((STI) < 96) {                                                          \
        const int tl_ = dir ? 95 - (STI) : (STI);                              \
        XA = *(const bf16x8*)(xTb + (size_t)tl_ * 64);                         \
        XB = *(const bf16x8*)(xTb + (size_t)tl_ * 64 + 32);                    \
    }

#define FSTEP(XA, XB, STI)                                                     \
    {                                                                          \
        const int t_ = dir ? 95 - (STI) : (STI);                               \
        U32x4 hu;                                                              \
        {                                                                      \
            int a0 = __shfl((int)pk0x, srcL0), a1 = __shfl((int)pk0y, srcL0);  \
            int a2 = __shfl((int)pk0x, srcL1), a3 = __shfl((int)pk0y, srcL1);  \
            int b0 = __shfl((int)pk1x, srcL0), b1 = __shfl((int)pk1y, srcL0);  \
            int b2 = __shfl((int)pk1x, srcL1), b3 = __shfl((int)pk1y, srcL1);  \
            hu.u[0] = sp ? (unsigned)b0 : (unsigned)a0;                        \
            hu.u[1] = sp ? (unsigned)b1 : (unsigned)a1;                        \
            hu.u[2] = sp ? (unsigned)b2 : (unsigned)a2;                        \
            hu.u[3] = sp ? (unsigned)b3 : (unsigned)a3;                        \
        }                                                                      \
        f32x4 ac[8];                                                           \
        _Pragma("unroll")                                                      \
        for (int tt = 0; tt < 8; ++tt) {                                       \
            f32x4 t0 = __builtin_amdgcn_mfma_f32_16x16x32_bf16(ax0[tt], XA, bc[tt], 0, 0, 0); \
            t0 = __builtin_amdgcn_mfma_f32_16x16x32_bf16(ax1[tt], XB, t0, 0, 0, 0);           \
            ac[tt] = __builtin_amdgcn_mfma_f32_16x16x32_bf16(ah[tt], hu.v, t0, 0, 0, 0);      \
        }                                                                      \
        _Pragma("unroll")                                                      \
        for (int s = 0; s < 2; ++s) {                                          \
            unsigned short hs[4];                                              \
            _Pragma("unroll")                                                  \
            for (int j = 0; j < 4; ++j) {                                      \
                const float iv = sigmf_(ac[0 + s][j]);                         \
                const float fv = sigmf_(ac[2 + s][j]);                         \
                const float gv = tanhf_(ac[4 + s][j]);                         \
                const float ov = sigmf_(ac[6 + s][j]);                         \
                cc[s][j] = fmaf(fv, cc[s][j], iv * gv);                        \
                hs[j] = f2bf(ov * tanhf_(cc[s][j]));                           \
            }                                                                  \
            const unsigned dlo = ((unsigned)hs[1] << 16) | hs[0];              \
            const unsigned dhi = ((unsigned)hs[3] << 16) | hs[2];              \
            if (s == 0) { pk0x = dlo; pk0y = dhi; } else { pk1x = dlo; pk1y = dhi; } \
            ushort4 hp; hp.x = hs[0]; hp.y = hs[1]; hp.z = hs[2]; hp.w = hs[3];\
            const int cbase = dir * 32 + s * 16 + rg * 4;                      \
            const size_t oidx = VERT                                           \
                ? ((((size_t)b * 96 + t_) * 96 + q) * 64 + cbase)              \
                : ((((size_t)b * 96 + q) * 96 + t_) * 64 + cbase);             \
            *(ushort4*)(outU + oidx) = hp;                                     \
        }                                                                      \
    }

template<int VERT>
__global__ __launch_bounds__(64, 1)
void lstm_fused(const unsigned short* __restrict__ xT,
                const float* __restrict__ wih_f, const float* __restrict__ whh_f,
                const float* __restrict__ bih_f, const float* __restrict__ bhh_f,
                const float* __restrict__ wih_b, const float* __restrict__ whh_b,
                const float* __restrict__ bih_b, const float* __restrict__ bhh_b,
                unsigned short* __restrict__ outU)
{
    const int lane = threadIdx.x;
    const int dir = blockIdx.x & 1, group = blockIdx.x >> 1;   // 192 groups x 2 dirs
    const int n_ = lane & 15, rg = lane >> 4;
    const int chain = group * 16 + n_;
    const int b = group / 6;
    const int q = (group - b * 6) * 16 + n_;

    const float* wih = dir ? wih_b : wih_f;
    const float* whh = dir ? whh_b : whh_f;
    const float* bih = dir ? bih_b : bih_f;
    const float* bhh = dir ? bhh_b : bhh_f;

    // Weight fragments (A-operand mapping validated by R9 refcheck):
    // lane (n_, rg): row = tile*16 + n_, k = rg*8..+8.
    bf16x8 ah[8], ax0[8], ax1[8];
    f32x4 bc[8];
#pragma unroll
    for (int tt = 0; tt < 8; ++tt) {
        const float* sh = whh + (size_t)(tt * 16 + n_) * 32 + rg * 8;
        const float* sx = wih + (size_t)(tt * 16 + n_) * 64 + rg * 8;
        float4 h0 = *(const float4*)sh, h1 = *(const float4*)(sh + 4);
        float4 x0 = *(const float4*)sx, x1 = *(const float4*)(sx + 4);
        float4 x2 = *(const float4*)(sx + 32), x3 = *(const float4*)(sx + 36);
        ah[tt][0] = (short)f2bf(h0.x); ah[tt][1] = (short)f2bf(h0.y);
        ah[tt][2] = (short)f2bf(h0.z); ah[tt][3] = (short)f2bf(h0.w);
        ah[tt][4] = (short)f2bf(h1.x); ah[tt][5] = (short)f2bf(h1.y);
        ah[tt][6] = (short)f2bf(h1.z); ah[tt][7] = (short)f2bf(h1.w);
        ax0[tt][0] = (short)f2bf(x0.x); ax0[tt][1] = (short)f2bf(x0.y);
        ax0[tt][2] = (short)f2bf(x0.z); ax0[tt][3] = (short)f2bf(x0.w);
        ax0[tt][4] = (short)f2bf(x1.x); ax0[tt][5] = (short)f2bf(x1.y);
        ax0[tt][6] = (short)f2bf(x1.z); ax0[tt][7] = (short)f2bf(x1.w);
        ax1[tt][0] = (short)f2bf(x2.x); ax1[tt][1] = (short)f2bf(x2.y);
        ax1[tt][2] = (short)f2bf(x2.z); ax1[tt][3] = (short)f2bf(x2.w);
        ax1[tt][4] = (short)f2bf(x3.x); ax1[tt][5] = (short)f2bf(x3.y);
        ax1[tt][6] = (short)f2bf(x3.z); ax1[tt][7] = (short)f2bf(x3.w);
#pragma unroll
        for (int j = 0; j < 4; ++j) {
            const int g = tt * 16 + rg * 4 + j;
            bc[tt][j] = bih[g] + bhh[g];
        }
    }

    // h-exchange sources: lane (n_, rg) needs cells rg*8..+8 = s-pack sp of
    // lanes (n_, (rg&1)*2) and (n_, (rg&1)*2+1).
    const int sp = rg >> 1;
    const int srcL0 = ((rg & 1) << 1) * 16 + n_;
    const int srcL1 = srcL0 + 16;

    const unsigned short* xTb = xT + (size_t)chain * 6144 + rg * 8;

    unsigned pk0x = 0, pk0y = 0, pk1x = 0, pk1y = 0;   // h packs (s=0 / s=1)
    float cc[2][4];
#pragma unroll
    for (int s = 0; s < 2; ++s)
#pragma unroll
        for (int j = 0; j < 4; ++j) cc[s][j] = 0.f;

    bf16x8 xa0, xb0, xa1, xb1, xa2, xb2;
    FLOAD(xa0, xb0, 0)
    FLOAD(xa1, xb1, 1)

    for (int st = 0; st < 96; st += 3) {
        FLOAD(xa2, xb2, st + 2) FSTEP(xa0, xb0, st)
        FLOAD(xa0, xb0, st + 3) FSTEP(xa1, xb1, st + 1)
        FLOAD(xa1, xb1, st + 4) FSTEP(xa2, xb2, st + 2)
    }
}

// ---------------------------------------------------------------------------
// Partial Gram (64x64) + channel-sum (64) of hh over this block's pixel chunk.
// ---------------------------------------------------------------------------
__global__ __launch_bounds__(256)
void gram_partial(const unsigned short* __restrict__ hh, float* __restrict__ part)
{
    __shared__ float xs[64][64];
    __shared__ float red[4160];
    const int tid = threadIdx.x;
    for (int e = tid; e < 4160; e += 256) red[e] = 0.0f;
    const int lane = tid & 63, wv = tid >> 6;
    const int li = lane >> 3, lj = lane & 7;
    float acc[8][8]; float macc[8];
#pragma unroll
    for (int i = 0; i < 8; ++i) {
        macc[i] = 0.f;
#pragma unroll
        for (int j = 0; j < 8; ++j) acc[i][j] = 0.f;
    }
    const size_t pix0 = (size_t)blockIdx.x * PIX_PER_BLOCK;
    for (int tile = 0; tile < PIX_PER_BLOCK / 64; ++tile) {
        __syncthreads();
        const unsigned short* src = hh + (pix0 + tile * 64) * 64;
#pragma unroll
        for (int r = 0; r < 4; ++r) {
            int idx4 = tid + 256 * r;
            ushort4 v = ((const ushort4*)src)[idx4];
            int fi = idx4 * 4; int px = fi >> 6; int c = fi & 63;
            xs[px][c] = bf2f(v.x); xs[px][c + 1] = bf2f(v.y);
            xs[px][c + 2] = bf2f(v.z); xs[px][c + 3] = bf2f(v.w);
        }
        __syncthreads();
        for (int p = wv * 16; p < wv * 16 + 16; ++p) {
            float4 ra = *(const float4*)&xs[p][8 * li];
            float4 rb = *(const float4*)&xs[p][8 * li + 4];
            float4 ca = *(const float4*)&xs[p][8 * lj];
            float4 cb = *(const float4*)&xs[p][8 * lj + 4];
            float r[8] = {ra.x, ra.y, ra.z, ra.w, rb.x, rb.y, rb.z, rb.w};
            float cl[8] = {ca.x, ca.y, ca.z, ca.w, cb.x, cb.y, cb.z, cb.w};
#pragma unroll
            for (int i = 0; i < 8; ++i) {
#pragma unroll
                for (int j = 0; j < 8; ++j) acc[i][j] = fmaf(r[i], cl[j], acc[i][j]);
            }
            if (lj == 0) {
#pragma unroll
                for (int i = 0; i < 8; ++i) macc[i] += r[i];
            }
        }
    }
    __syncthreads();
#pragma unroll
    for (int i = 0; i < 8; ++i)
#pragma unroll
        for (int j = 0; j < 8; ++j)
            atomicAdd(&red[(8 * li + i) * 64 + 8 * lj + j], acc[i][j]);
    if (lj == 0)
        for (int i = 0; i < 8; ++i) atomicAdd(&red[4096 + 8 * li + i], macc[i]);
    __syncthreads();
    for (int e = tid; e < 4160; e += 256) part[(size_t)blockIdx.x * 4160 + e] = red[e];
}

__global__ void gram_reduce(const float* __restrict__ part, float* __restrict__ M)
{
    int e = blockIdx.x * 256 + threadIdx.x;
    if (e >= 4160) return;
    double s = 0.0;
    for (int p = 0; p < GRAM_BLOCKS; ++p) s += (double)part[(size_t)p * 4160 + e];
    M[e] = (float)s;
}

// Per-output-channel affine coefficients A,B such that out = A*(w_o . u) + B.
// Weights rounded through bf16 so A/B match the bf16-MFMA conv exactly.
__global__ __launch_bounds__(256)
void stats_kernel(const float* __restrict__ M, const float* __restrict__ cw,
                  const float* __restrict__ cb, const float* __restrict__ bg,
                  const float* __restrict__ bb,
                  float* __restrict__ Aout, float* __restrict__ Bout)
{
    __shared__ float Ml[4160];
    const int tid = threadIdx.x;
    for (int e = tid; e < 4160; e += 256) Ml[e] = M[e];
    __syncthreads();
    float wr[64];
#pragma unroll
    for (int c = 0; c < 64; ++c) wr[c] = bf2f(f2bf(cw[tid * 64 + c]));
    float s1 = 0.f;
#pragma unroll
    for (int c = 0; c < 64; ++c) s1 = fmaf(wr[c], Ml[4096 + c], s1);
    float s2 = 0.f;
    for (int c = 0; c < 64; ++c) {
        const float* Mr = &Ml[c * 64];
        float t = 0.f;
#pragma unroll
        for (int d = 0; d < 64; ++d) t = fmaf(wr[d], Mr[d], t);
        s2 = fmaf(wr[c], t, s2);
    }
    const double invN = 1.0 / (double)NPIX;
    double cbo = (double)cb[tid];
    double mu = (double)s1 * invN + cbo;
    double ey2 = (double)s2 * invN + 2.0 * cbo * ((double)s1 * invN) + cbo * cbo;
    double var = ey2 - mu * mu;
    double A = (double)bg[tid] / sqrt(var + 1e-5);
    Aout[tid] = (float)A;
    Bout[tid] = (float)((double)bb[tid] + A * (cbo - mu));
}

// ---------------------------------------------------------------------------
// Fused 1x1 conv + BN apply via MFMA. Block = (b,w): D[96 h][256 o].
// ---------------------------------------------------------------------------
__global__ __launch_bounds__(512, 2)
void conv_bn_kernel(const unsigned short* __restrict__ hh, const float* __restrict__ cw,
                    const float* __restrict__ Aarr, const float* __restrict__ Barr,
                    float* __restrict__ out)
{
    __shared__ alignas(16) unsigned char UsB[96 * 128];    // bf16 U, swizzled
    __shared__ alignas(16) unsigned char WtB[256 * 128];   // bf16 conv W, swizzled

    const int tid = threadIdx.x;
    const int b = blockIdx.x / 96, w = blockIdx.x % 96;

    for (int i4 = tid; i4 < 4096; i4 += 512) {
        int wrow = i4 >> 4, k4 = i4 & 15;
        float4 v = *(const float4*)(cw + (size_t)wrow * 64 + k4 * 4);
        ushort4 p; p.x = f2bf(v.x); p.y = f2bf(v.y); p.z = f2bf(v.z); p.w = f2bf(v.w);
        *(ushort4*)(WtB + wrow * 128 + ((k4 * 8) ^ ((wrow & 7) << 4))) = p;
    }
    for (int i = tid; i < 1536; i += 512) {
        int row = i >> 4, k4 = i & 15;   // row = h
        ushort4 p = *(const ushort4*)(hh + (((size_t)b * 96 + row) * 96 + w) * 64 + k4 * 4);
        *(ushort4*)(UsB + row * 128 + ((k4 * 8) ^ ((row & 7) << 4))) = p;
    }
    __syncthreads();

    const int wv = tid >> 6, lane = tid & 63;
    const int mbase = (wv >> 2) * 48, nbase = (wv & 3) * 64;
    const int lrow = lane & 15, lk = (lane >> 4) * 8;

    f32x4 acc[3][4];
#pragma unroll
    for (int m = 0; m < 3; ++m)
#pragma unroll
        for (int n = 0; n < 4; ++n)
            acc[m][n] = (f32x4){0.f, 0.f, 0.f, 0.f};

#pragma unroll
    for (int ks = 0; ks < 2; ++ks) {
        const int kb = (ks * 32 + lk) * 2;
        bf16x8 am[3], bn[4];
#pragma unroll
        for (int m = 0; m < 3; ++m) {
            int row = mbase + m * 16 + lrow;
            am[m] = *(const bf16x8*)(UsB + row * 128 + (kb ^ ((row & 7) << 4)));
        }
#pragma unroll
        for (int n = 0; n < 4; ++n) {
            int o = nbase + n * 16 + lrow;
            bn[n] = *(const bf16x8*)(WtB + o * 128 + (kb ^ ((o & 7) << 4)));
        }
#pragma unroll
        for (int m = 0; m < 3; ++m)
#pragma unroll
            for (int n = 0; n < 4; ++n)
                acc[m][n] = __builtin_amdgcn_mfma_f32_16x16x32_bf16(am[m], bn[n], acc[m][n], 0, 0, 0);
    }

    const int hbase0 = (lane >> 4) * 4;
#pragma unroll
    for (int n = 0; n < 4; ++n) {
        const int o = nbase + n * 16 + lrow;
        const float Ao = Aarr[o], Bo = Barr[o];
        float* obase = out + (((size_t)b * 256 + o) * 96 + w) * 96;
#pragma unroll
        for (int m = 0; m < 3; ++m) {
            const int h0 = mbase + m * 16 + hbase0;
            float4 res;
            res.x = fmaf(Ao, acc[m][n][0], Bo);
            res.y = fmaf(Ao, acc[m][n][1], Bo);
            res.z = fmaf(Ao, acc[m][n][2], Bo);
            res.w = fmaf(Ao, acc[m][n][3], Bo);
            *(float4*)(obase + h0) = res;
        }
    }
}

extern "C" void kernel_launch(void* const* d_in, const int* in_sizes, int n_in,
                              void* d_out, int out_size, void* d_ws, size_t ws_size,
                              hipStream_t stream)
{
    const float* x       = (const float*)d_in[0];
    const float* v_wih_f = (const float*)d_in[1];
    const float* v_whh_f = (const float*)d_in[2];
    const float* v_bih_f = (const float*)d_in[3];
    const float* v_bhh_f = (const float*)d_in[4];
    const float* v_wih_b = (const float*)d_in[5];
    const float* v_whh_b = (const float*)d_in[6];
    const float* v_bih_b = (const float*)d_in[7];
    const float* v_bhh_b = (const float*)d_in[8];
    const float* h_wih_f = (const float*)d_in[9];
    const float* h_whh_f = (const float*)d_in[10];
    const float* h_bih_f = (const float*)d_in[11];
    const float* h_bhh_f = (const float*)d_in[12];
    const float* h_wih_b = (const float*)d_in[13];
    const float* h_whh_b = (const float*)d_in[14];
    const float* h_bih_b = (const float*)d_in[15];
    const float* h_bhh_b = (const float*)d_in[16];
    const float* conv_w  = (const float*)d_in[17];
    const float* conv_b  = (const float*)d_in[18];
    const float* bn_g    = (const float*)d_in[19];
    const float* bn_b    = (const float*)d_in[20];
    float* out = (float*)d_out;

    // d_out (302 MB) doubles as scratch before conv_bn rewrites all of it:
    //   front 37.7 MB: xT (bf16 [chain=(b,w)][t=h][c]) — dead after pass 1
    //   tail 37.7 MB: v (bf16 [chain=(b,h)][t=w][c])  — vertical LSTM output
    const size_t v_elems = (size_t)Bn * Hn * Wn * 64;   // 18,874,368 bf16
    unsigned short* v_buf = (unsigned short*)(out + (size_t)out_size) - v_elems;
    unsigned short* xT = (unsigned short*)d_out;

    // workspace layout (~40 MB)
    unsigned short* hh = (unsigned short*)d_ws;                       // bf16 [B,H,W,64]
    char* wsb = (char*)d_ws;
    float* part = (float*)(wsb + 37748736);                           // 128 x 4160 f32
    float* M    = (float*)(wsb + 37748736 + 2129920);                 // 4160 f32
    float* Aarr = M + 4160;
    float* Barr = Aarr + 256;

    // vertical pass: transpose x, then fused projection+recurrence
    transpose_x<<<3072, 256, 0, stream>>>(x, xT);
    lstm_fused<1><<<384, 64, 0, stream>>>(xT, v_wih_f, v_whh_f, v_bih_f, v_bhh_f,
                                          v_wih_b, v_whh_b, v_bih_b, v_bhh_b, v_buf);
    // horizontal pass: v is already [chain][t][c]
    lstm_fused<0><<<384, 64, 0, stream>>>(v_buf, h_wih_f, h_whh_f, h_bih_f, h_bhh_f,
                                          h_wih_b, h_whh_b, h_bih_b, h_bhh_b, hh);
    // conv + BN (affine-folded via Gram-matrix stats)
    gram_partial<<<GRAM_BLOCKS, 256, 0, stream>>>(hh, part);
    gram_reduce<<<17, 256, 0, stream>>>(part, M);
    stats_kernel<<<1, 256, 0, stream>>>(M, conv_w, conv_b, bn_g, bn_b, Aarr, Barr);
    conv_bn_kernel<<<3072, 512, 0, stream>>>(hh, conv_w, Aarr, Barr, out);
}